// Round 24
// baseline (109.731 us; speedup 1.0000x reference)
//
#include <hip/hip_runtime.h>
#include <hip/hip_bf16.h>

typedef __bf16 bf16x8 __attribute__((ext_vector_type(8)));
typedef float f32x4 __attribute__((ext_vector_type(4)));

__device__ __forceinline__ unsigned short f2b(float f) {
    union { float f; unsigned int u; } v; v.f = f;
    unsigned int r = (v.u + 0x7FFFu + ((v.u >> 16) & 1u)) >> 16;
    return (unsigned short)r;
}

__device__ __forceinline__ unsigned int cvtpk(float lo, float hi) {
    unsigned int r;
    asm("v_cvt_pk_bf16_f32 %0, %1, %2" : "=v"(r) : "v"(lo), "v"(hi));
    return r;
}

__device__ __forceinline__ void gload_lds16(const void* g, void* l) {
    __builtin_amdgcn_global_load_lds((__attribute__((address_space(1))) void*)g,
                                     (__attribute__((address_space(3))) void*)l,
                                     16, 0, 0);
}

// ---- prepass: pure-streaming convert + transposes ----

__global__ __launch_bounds__(256)
void prepass_kernel(const float* __restrict__ x, const float* __restrict__ wg,
                    const float* __restrict__ wq, const float* __restrict__ wo,
                    unsigned short* __restrict__ xb,
                    unsigned short* __restrict__ outq, unsigned short* __restrict__ outo,
                    unsigned short* __restrict__ wgT) {
    __shared__ float tt[32][33];
    const int t = threadIdx.x;
    if (blockIdx.x < 2048) {
        size_t idx = ((size_t)blockIdx.x * 256 + t) * 8;
        float4 f0 = *(const float4*)(x + idx);
        float4 f1 = *(const float4*)(x + idx + 4);
        ushort4 u0, u1;
        u0.x = f2b(f0.x); u0.y = f2b(f0.y); u0.z = f2b(f0.z); u0.w = f2b(f0.w);
        u1.x = f2b(f1.x); u1.y = f2b(f1.y); u1.z = f2b(f1.z); u1.w = f2b(f1.w);
        *(ushort4*)(xb + idx) = u0;
        *(ushort4*)(xb + idx + 4) = u1;
    } else if (blockIdx.x < 6144) {
        const int bx = blockIdx.x - 2048;
        const int colTile = bx & 127;
        const int r0 = (bx >> 7) * 32;
        const float* in;
        unsigned short* out;
        int C, c0;
        if (colTile < 96) { in = wq; out = outq; C = 3072; c0 = colTile * 32; }
        else              { in = wo; out = outo; C = 1024; c0 = (colTile - 96) * 32; }
        const int tx = t & 31, ty = t >> 5;
#pragma unroll
        for (int i = 0; i < 4; i++)
            tt[ty + i * 8][tx] = in[(size_t)(r0 + ty + i * 8) * C + c0 + tx];
        __syncthreads();
#pragma unroll
        for (int i = 0; i < 4; i++)
            out[(size_t)(c0 + ty + i * 8) * 1024 + r0 + tx] = f2b(tt[tx][ty + i * 8]);
    } else {
        const int local = blockIdx.x - 6144;
        const int base = local * 4096 + t * 16;
        const int f = base >> 4;
#pragma unroll
        for (int j = 0; j < 16; j++)
            wgT[j * 1024 + f] = f2b(wg[base + j]);
    }
}

// ---- gates via MFMA ----

__global__ __launch_bounds__(256)
void gates_mfma_kernel(const unsigned short* __restrict__ xb,
                       const unsigned short* __restrict__ wgT,
                       float* __restrict__ gates) {
    __shared__ float comb[4][16][16];
    const int lane = threadIdx.x & 63;
    const int w = threadIdx.x >> 6;
    const int ql = lane & 15;
    const int g = lane >> 4;
    const int n0 = blockIdx.x * 16;

    f32x4 acc = (f32x4){0.f, 0.f, 0.f, 0.f};
    const int kb = w * 256;
#pragma unroll
    for (int kk = 0; kk < 256; kk += 32) {
        bf16x8 a = *(const bf16x8*)(wgT + ql * 1024 + kb + kk + g * 8);
        bf16x8 bfr = *(const bf16x8*)(xb + (size_t)(n0 + ql) * 1024 + kb + kk + g * 8);
        acc = __builtin_amdgcn_mfma_f32_16x16x32_bf16(a, bfr, acc, 0, 0, 0);
    }
#pragma unroll
    for (int r = 0; r < 4; r++) comb[w][g * 4 + r][ql] = acc[r];
    __syncthreads();
    if (w == 0) {
        const float LOG2E = 1.4426950408889634f;
        int row = n0 + ql;
        int b = row >> 11, n = row & 2047;
#pragma unroll
        for (int r = 0; r < 4; r++) {
            int h = g * 4 + r;
            float tot = comb[0][h][ql] + comb[1][h][ql] + comb[2][h][ql] + comb[3][h][ql];
            float sg = __builtin_amdgcn_rcpf(1.f + __builtin_amdgcn_exp2f(-tot * LOG2E));
            gates[((size_t)(b * 16 + h)) * 2048 + n] = sg;
        }
    }
}

// ---------------- GEMM: C = A[M][K] * Bt[N][K]^T, bf16 in, fp32 acc ----------------
// BK=32, double-buffered staging (one barrier/iter). Generalized tile:
//   BM x (64*WN) with NW waves as (NW/WN) x WN; each wave's 64x64 (or 32x64)
//   sub-tile code identical to the verified R22 wave code.
// gemm0: <0, 256, 2, 8> = 256x128, 8 waves, 48KB LDS -> 6 waves/SIMD.
// gemm1: <1, 128, 1, 4> = 128x64, 4 waves (identical to R22 codegen).
// EPI 0: Q (x0.125), K as [b][h][n][d]; V directly in Vp[bh][d][permC(nn)].
// EPI 1: fp32 out [M][N].

template <int EPI, int BM, int WN, int NW>
__global__ __launch_bounds__(NW * 64)
void gemm_bt_kernel(const unsigned short* __restrict__ A,
                    const unsigned short* __restrict__ Bt,
                    int M, int N, int K,
                    unsigned short* __restrict__ outQ,
                    unsigned short* __restrict__ outK,
                    unsigned short* __restrict__ outV,
                    float* __restrict__ outF) {
    constexpr int WM = NW / WN;          // wave-rows
    constexpr int RPW = BM / WM;         // rows per wave (64 or 32)
    constexpr int MF = RPW / 16;         // m fragments per wave
    constexpr int BN = 64 * WN;
    constexpr int CA = (BM / 16) / NW;   // A 16-row chunks per wave
    __shared__ unsigned short As[2][BM * 32];
    __shared__ unsigned short Bs[2][BN * 32];
    const int lane = threadIdx.x & 63;
    const int w = threadIdx.x >> 6;
    const int wr = w / WN, wc = w % WN;
    const int tm = blockIdx.y * BM;
    const int tn = blockIdx.x * BN;

    f32x4 acc[MF][4];
#pragma unroll
    for (int m = 0; m < MF; m++)
#pragma unroll
        for (int n = 0; n < 4; n++) acc[m][n] = (f32x4){0.f, 0.f, 0.f, 0.f};

    const int sRow = lane >> 2;
    const int sCol = (lane & 3) * 8;
    const int fragA = (wr * RPW + (lane & 15)) * 32 + (lane >> 4) * 8;
    const int fragB = (wc * 64 + (lane & 15)) * 32 + (lane >> 4) * 8;

    auto STAGE = [&](int k0, int buf) {
#pragma unroll
        for (int i = 0; i < CA; i++) {
            int chunk = w * CA + i;
            int r = chunk * 16 + sRow;
            gload_lds16(A + (size_t)(tm + r) * K + k0 + sCol, (void*)(As[buf] + chunk * 512));
        }
        // B: BN/16 chunks, one per wave (all current configs have BN/16 <= NW)
        if (w < BN / 16) {
            int r = w * 16 + sRow;
            gload_lds16(Bt + (size_t)(tn + r) * K + k0 + sCol, (void*)(Bs[buf] + w * 512));
        }
    };

    STAGE(0, 0);
    __syncthreads();
    int cur = 0;
    for (int k0 = 0; k0 < K; k0 += 32) {
        if (k0 + 32 < K) STAGE(k0 + 32, cur ^ 1);
        bf16x8 af[MF], bg[4];
#pragma unroll
        for (int m = 0; m < MF; m++) af[m] = *(const bf16x8*)(As[cur] + fragA + m * 16 * 32);
#pragma unroll
        for (int n = 0; n < 4; n++) bg[n] = *(const bf16x8*)(Bs[cur] + fragB + n * 16 * 32);
#pragma unroll
        for (int m = 0; m < MF; m++)
#pragma unroll
            for (int n = 0; n < 4; n++)
                acc[m][n] = __builtin_amdgcn_mfma_f32_16x16x32_bf16(af[m], bg[n], acc[m][n], 0, 0, 0);
        __syncthreads();
        cur ^= 1;
    }

#pragma unroll
    for (int m = 0; m < MF; m++) {
        int row = tm + wr * RPW + m * 16 + (lane >> 4) * 4;
#pragma unroll
        for (int n = 0; n < 4; n++) {
            int col = tn + wc * 64 + n * 16 + (lane & 15);
            if (EPI == 0) {
                int which = col >> 10;
                int hh = (col >> 6) & 15;
                int d = col & 63;
                int b0 = row >> 11;
                int nn = row & 2047;             // nn % 4 == 0
                size_t bh = (size_t)(b0 * 16 + hh);
                if (which == 2) {
                    int i6 = nn & 63;
                    int pc = (nn & ~63) + ((i6 >> 2) & 3) * 16 + ((i6 >> 4) & 3) * 4;
                    ushort4 st;
                    st.x = f2b(acc[m][n][0]);
                    st.y = f2b(acc[m][n][1]);
                    st.z = f2b(acc[m][n][2]);
                    st.w = f2b(acc[m][n][3]);
                    *(ushort4*)(outV + bh * 131072 + (size_t)d * 2048 + pc) = st;
                } else if (which == 0) {
                    size_t off = (bh * 2048 + nn) * 64 + d;
#pragma unroll
                    for (int r = 0; r < 4; r++)
                        outQ[off + (size_t)r * 64] = f2b(acc[m][n][r] * 0.125f);
                } else {
                    size_t off = (bh * 2048 + nn) * 64 + d;
#pragma unroll
                    for (int r = 0; r < 4; r++)
                        outK[off + (size_t)r * 64] = f2b(acc[m][n][r]);
                }
            } else {
#pragma unroll
                for (int r = 0; r < 4; r++)
                    outF[(size_t)(row + r) * N + col] = acc[m][n][r];
            }
        }
    }
}

// ---------------- flash attention (R23: Latin-square 1024 blocks) ----------------
// 1024 single-qt blocks (4 waves x 16 q-rows, 32KB LDS dbuf), Latin-square
// placement: bh = 4x + (c&3); s = c>>2; qt(j) = {31-s, s, 23-s, 8+s} ->
// every CU gets exactly 66 kv-iters; 4 blocks/CU = 4 waves/SIMD.
// Diagonal peeled; poly softcap; XOR-swizzled ds_read_b128; s_setprio.

__global__ __launch_bounds__(256)
void attn_kernel(const unsigned short* __restrict__ Q,
                 const unsigned short* __restrict__ Kg,
                 const unsigned short* __restrict__ Vp,
                 const float* __restrict__ Gates,
                 unsigned short* __restrict__ Out) {
    __shared__ unsigned short lds[2][2][64][64];   // [dbuf][K|V][row][col] = 32KB

    const int lane = threadIdx.x & 63;
    const int w = threadIdx.x >> 6;
    const int g = lane >> 4;
    const int ql = lane & 15;
    const int sw = ql & 7;
    const int srow = lane >> 3;
    const int sch = lane & 7;

    const int x = blockIdx.x & 7;            // XCD
    const int c = (blockIdx.x >> 3) & 31;    // CU within XCD
    const int j = blockIdx.x >> 8;           // co-residency round 0..3
    const int bh = x * 4 + (c & 3);
    const int s = c >> 2;                    // 0..7
    const int qt = (j == 0) ? (31 - s) : (j == 1) ? s : (j == 2) ? (23 - s) : (8 + s);
    const int b = bh >> 4;
    const int h = bh & 15;

    const size_t headBase = (size_t)bh * 2048 * 64;
    const size_t vBase = (size_t)bh * 131072;

    const int koff0 = ((g) ^ sw) * 8;
    const int koff1 = ((g + 4) ^ sw) * 8;
    const int voff0 = ((2 * g) ^ sw) * 8;
    const int voff1 = ((2 * g + 1) ^ sw) * 8;

    const int ch = sch ^ srow;
    const unsigned short* kSt0 = Kg + headBase + (size_t)(w * 16 + srow) * 64 + ch * 8;
    const unsigned short* kSt1 = kSt0 + 8 * 64;
    const unsigned short* vSt0 = Vp + vBase + (size_t)(w * 16 + srow) * 2048 + ch * 8;
    const unsigned short* vSt1 = vSt0 + 8 * 2048;

    auto STAGE = [&](int jn, int buf) {
        gload_lds16(kSt0 + (size_t)jn * 4096, (void*)&lds[buf][0][w * 16][0]);
        gload_lds16(kSt1 + (size_t)jn * 4096, (void*)&lds[buf][0][w * 16 + 8][0]);
        gload_lds16(vSt0 + jn * 64, (void*)&lds[buf][1][w * 16][0]);
        gload_lds16(vSt1 + jn * 64, (void*)&lds[buf][1][w * 16 + 8][0]);
    };

    const float LOG2E = 1.4426950408889634f;
    const float LC1 = -1.9235933878519511e-4f;   // LOG2E * -(1/3)/2500
    const float LC2 = 3.0777494205631219e-8f;    // LOG2E * (2/15)/2500^2

    const int qglob = qt * 64 + w * 16 + ql;
    const unsigned short* qp = Q + headBase + (size_t)qglob * 64 + g * 8;
    bf16x8 qa0 = *(const bf16x8*)qp;
    bf16x8 qa1 = *(const bf16x8*)(qp + 32);

    float lsum = 0.f;
    f32x4 o[4];
#pragma unroll
    for (int n = 0; n < 4; n++) o[n] = (f32x4){0.f, 0.f, 0.f, 0.f};

    auto COMPUTE = [&](int jt, int bb, bool diag) {
        const unsigned short* KL = &lds[bb][0][0][0];
        const unsigned short* VL = &lds[bb][1][0][0];

        f32x4 s4[4];
        __builtin_amdgcn_s_setprio(1);
#pragma unroll
        for (int n = 0; n < 4; n++) {
            const unsigned short* kr = KL + (16 * n + ql) * 64;
            bf16x8 k0 = *(const bf16x8*)(kr + koff0);
            bf16x8 k1 = *(const bf16x8*)(kr + koff1);
            f32x4 sv = (f32x4){0.f, 0.f, 0.f, 0.f};
            sv = __builtin_amdgcn_mfma_f32_16x16x32_bf16(k0, qa0, sv, 0, 0, 0);
            sv = __builtin_amdgcn_mfma_f32_16x16x32_bf16(k1, qa1, sv, 0, 0, 0);
            s4[n] = sv;
        }
        __builtin_amdgcn_s_setprio(0);

        float rs = 0.f;
#pragma unroll
        for (int n = 0; n < 4; n++) {
            int k0c = jt * 64 + n * 16 + 4 * g;
#pragma unroll
            for (int r = 0; r < 4; r++) {
                float xx = s4[n][r];
                float x2 = xx * xx;
                float e2 = xx * __builtin_fmaf(x2, __builtin_fmaf(x2, LC2, LC1), LOG2E);
                if (diag && (k0c + r > qglob)) e2 = -1e30f;
                float p = __builtin_amdgcn_exp2f(e2);
                s4[n][r] = p;
                rs += p;
            }
        }
        lsum += rs;

        union PU { unsigned int u[4]; bf16x8 v; };
        PU p0, p1;
        p0.u[0] = cvtpk(s4[0][0], s4[0][1]);
        p0.u[1] = cvtpk(s4[0][2], s4[0][3]);
        p0.u[2] = cvtpk(s4[1][0], s4[1][1]);
        p0.u[3] = cvtpk(s4[1][2], s4[1][3]);
        p1.u[0] = cvtpk(s4[2][0], s4[2][1]);
        p1.u[1] = cvtpk(s4[2][2], s4[2][3]);
        p1.u[2] = cvtpk(s4[3][0], s4[3][1]);
        p1.u[3] = cvtpk(s4[3][2], s4[3][3]);

        __builtin_amdgcn_s_setprio(1);
#pragma unroll
        for (int n = 0; n < 4; n++) {
            const unsigned short* vr = VL + (16 * n + ql) * 64;
            bf16x8 vA = *(const bf16x8*)(vr + voff0);
            bf16x8 vB = *(const bf16x8*)(vr + voff1);
            o[n] = __builtin_amdgcn_mfma_f32_16x16x32_bf16(vA, p0.v, o[n], 0, 0, 0);
            o[n] = __builtin_amdgcn_mfma_f32_16x16x32_bf16(vB, p1.v, o[n], 0, 0, 0);
        }
        __builtin_amdgcn_s_setprio(0);
    };

    STAGE(0, 0);
    __syncthreads();

    for (int jt = 0; jt < qt; ++jt) {
        const int bb = jt & 1;
        STAGE(jt + 1, bb ^ 1);
        COMPUTE(jt, bb, false);
        __syncthreads();
    }
    COMPUTE(qt, qt & 1, true);

    float l = lsum;
    l += __shfl_xor(l, 16);
    l += __shfl_xor(l, 32);
    float gate = Gates[(size_t)bh * 2048 + qglob];
    float inv = gate / l;
    unsigned short* orow = Out + ((size_t)(b * 2048) + qglob) * 1024 + h * 64;
#pragma unroll
    for (int n = 0; n < 4; n++) {
        ushort4 st;
        st.x = f2b(o[n][0] * inv);
        st.y = f2b(o[n][1] * inv);
        st.z = f2b(o[n][2] * inv);
        st.w = f2b(o[n][3] * inv);
        *(ushort4*)(orow + n * 16 + 4 * g) = st;
    }
}

// ---------------- launch ----------------

extern "C" void kernel_launch(void* const* d_in, const int* in_sizes, int n_in,
                              void* d_out, int out_size, void* d_ws, size_t ws_size,
                              hipStream_t stream) {
    const float* x       = (const float*)d_in[0];   // [2][2048][1024]
    const float* w_qkv   = (const float*)d_in[1];   // [1024][3072]
    const float* w_gates = (const float*)d_in[2];   // [1024][16]
    const float* w_out   = (const float*)d_in[3];   // [1024][1024]
    float* out = (float*)d_out;                     // [2][2048][1024]

    char* ws = (char*)d_ws;
    unsigned short* x_bf  = (unsigned short*)(ws);                      // 8 MB
    unsigned short* wqkvT = (unsigned short*)(ws + ((size_t)8  << 20)); // 6 MB
    unsigned short* woutT = (unsigned short*)(ws + ((size_t)14 << 20)); // 2 MB
    unsigned short* qB    = (unsigned short*)(ws + ((size_t)16 << 20)); // 8 MB
    unsigned short* kB    = (unsigned short*)(ws + ((size_t)24 << 20)); // 8 MB
    unsigned short* vP    = (unsigned short*)(ws + ((size_t)32 << 20)); // 8 MB (permuted V)
    float*          gates = (float*)(ws + ((size_t)40 << 20));          // 256 KB
    unsigned short* wgT   = (unsigned short*)(ws + ((size_t)40 << 20) + (512 << 10)); // 32 KB
    unsigned short* attnO = (unsigned short*)(ws + ((size_t)41 << 20)); // 8 MB

    prepass_kernel<<<dim3(6148), dim3(256), 0, stream>>>(
        x, w_gates, w_qkv, w_out, x_bf, wqkvT, woutT, wgT);

    gates_mfma_kernel<<<dim3(256), dim3(256), 0, stream>>>(x_bf, wgT, gates);

    gemm_bt_kernel<0, 256, 2, 8><<<dim3(3072 / 128, 4096 / 256), dim3(512), 0, stream>>>(
        x_bf, wqkvT, 4096, 3072, 1024, qB, kB, vP, (float*)nullptr);

    attn_kernel<<<dim3(1024), dim3(256), 0, stream>>>(qB, kB, vP, gates, attnO);

    gemm_bt_kernel<1, 128, 1, 4><<<dim3(1024 / 64, 4096 / 128), dim3(256), 0, stream>>>(
        attnO, woutT, 4096, 1024, 1024, nullptr, nullptr, nullptr, out);
}

// Round 25
// 107.728 us; speedup vs baseline: 1.0186x; 1.0186x over previous
//
#include <hip/hip_runtime.h>
#include <hip/hip_bf16.h>

typedef __bf16 bf16x8 __attribute__((ext_vector_type(8)));
typedef float f32x4 __attribute__((ext_vector_type(4)));

__device__ __forceinline__ unsigned short f2b(float f) {
    union { float f; unsigned int u; } v; v.f = f;
    unsigned int r = (v.u + 0x7FFFu + ((v.u >> 16) & 1u)) >> 16;
    return (unsigned short)r;
}

__device__ __forceinline__ unsigned int cvtpk(float lo, float hi) {
    unsigned int r;
    asm("v_cvt_pk_bf16_f32 %0, %1, %2" : "=v"(r) : "v"(lo), "v"(hi));
    return r;
}

__device__ __forceinline__ void gload_lds16(const void* g, void* l) {
    __builtin_amdgcn_global_load_lds((__attribute__((address_space(1))) void*)g,
                                     (__attribute__((address_space(3))) void*)l,
                                     16, 0, 0);
}

// ---- prepass: pure-streaming convert + transposes ----

__global__ __launch_bounds__(256)
void prepass_kernel(const float* __restrict__ x, const float* __restrict__ wg,
                    const float* __restrict__ wq, const float* __restrict__ wo,
                    unsigned short* __restrict__ xb,
                    unsigned short* __restrict__ outq, unsigned short* __restrict__ outo,
                    unsigned short* __restrict__ wgT) {
    __shared__ float tt[32][33];
    const int t = threadIdx.x;
    if (blockIdx.x < 2048) {
        size_t idx = ((size_t)blockIdx.x * 256 + t) * 8;
        float4 f0 = *(const float4*)(x + idx);
        float4 f1 = *(const float4*)(x + idx + 4);
        ushort4 u0, u1;
        u0.x = f2b(f0.x); u0.y = f2b(f0.y); u0.z = f2b(f0.z); u0.w = f2b(f0.w);
        u1.x = f2b(f1.x); u1.y = f2b(f1.y); u1.z = f2b(f1.z); u1.w = f2b(f1.w);
        *(ushort4*)(xb + idx) = u0;
        *(ushort4*)(xb + idx + 4) = u1;
    } else if (blockIdx.x < 6144) {
        const int bx = blockIdx.x - 2048;
        const int colTile = bx & 127;
        const int r0 = (bx >> 7) * 32;
        const float* in;
        unsigned short* out;
        int C, c0;
        if (colTile < 96) { in = wq; out = outq; C = 3072; c0 = colTile * 32; }
        else              { in = wo; out = outo; C = 1024; c0 = (colTile - 96) * 32; }
        const int tx = t & 31, ty = t >> 5;
#pragma unroll
        for (int i = 0; i < 4; i++)
            tt[ty + i * 8][tx] = in[(size_t)(r0 + ty + i * 8) * C + c0 + tx];
        __syncthreads();
#pragma unroll
        for (int i = 0; i < 4; i++)
            out[(size_t)(c0 + ty + i * 8) * 1024 + r0 + tx] = f2b(tt[tx][ty + i * 8]);
    } else {
        const int local = blockIdx.x - 6144;
        const int base = local * 4096 + t * 16;
        const int f = base >> 4;
#pragma unroll
        for (int j = 0; j < 16; j++)
            wgT[j * 1024 + f] = f2b(wg[base + j]);
    }
}

// ---- gates via MFMA ----

__global__ __launch_bounds__(256)
void gates_mfma_kernel(const unsigned short* __restrict__ xb,
                       const unsigned short* __restrict__ wgT,
                       float* __restrict__ gates) {
    __shared__ float comb[4][16][16];
    const int lane = threadIdx.x & 63;
    const int w = threadIdx.x >> 6;
    const int ql = lane & 15;
    const int g = lane >> 4;
    const int n0 = blockIdx.x * 16;

    f32x4 acc = (f32x4){0.f, 0.f, 0.f, 0.f};
    const int kb = w * 256;
#pragma unroll
    for (int kk = 0; kk < 256; kk += 32) {
        bf16x8 a = *(const bf16x8*)(wgT + ql * 1024 + kb + kk + g * 8);
        bf16x8 bfr = *(const bf16x8*)(xb + (size_t)(n0 + ql) * 1024 + kb + kk + g * 8);
        acc = __builtin_amdgcn_mfma_f32_16x16x32_bf16(a, bfr, acc, 0, 0, 0);
    }
#pragma unroll
    for (int r = 0; r < 4; r++) comb[w][g * 4 + r][ql] = acc[r];
    __syncthreads();
    if (w == 0) {
        const float LOG2E = 1.4426950408889634f;
        int row = n0 + ql;
        int b = row >> 11, n = row & 2047;
#pragma unroll
        for (int r = 0; r < 4; r++) {
            int h = g * 4 + r;
            float tot = comb[0][h][ql] + comb[1][h][ql] + comb[2][h][ql] + comb[3][h][ql];
            float sg = __builtin_amdgcn_rcpf(1.f + __builtin_amdgcn_exp2f(-tot * LOG2E));
            gates[((size_t)(b * 16 + h)) * 2048 + n] = sg;
        }
    }
}

// ---------------- GEMM: C = A[M][K] * Bt[N][K]^T, bf16 in, fp32 acc ----------------
// BK=32, double-buffered staging (one barrier/iter). Generalized tile:
//   BM x (64*WN) with NW waves as (NW/WN) x WN.
// gemm0: <0, 128, 2, 8> = 128x128 tile, 8 waves (32x64 sub-tile each, MF=2),
//   32KB LDS, grid 768 -> 3 blocks/CU = 24 waves/CU (2x R23's residency).
//   B chunks = 8 = NW (one per wave); A chunks CA = 1 per wave. Verified.
// gemm1: <1, 128, 1, 4> = 128x64, 4 waves (R24-verified).
// EPI 0: Q (x0.125), K as [b][h][n][d]; V directly in Vp[bh][d][permC(nn)].
// EPI 1: fp32 out [M][N].

template <int EPI, int BM, int WN, int NW>
__global__ __launch_bounds__(NW * 64)
void gemm_bt_kernel(const unsigned short* __restrict__ A,
                    const unsigned short* __restrict__ Bt,
                    int M, int N, int K,
                    unsigned short* __restrict__ outQ,
                    unsigned short* __restrict__ outK,
                    unsigned short* __restrict__ outV,
                    float* __restrict__ outF) {
    constexpr int WM = NW / WN;          // wave-rows
    constexpr int RPW = BM / WM;         // rows per wave (64 or 32)
    constexpr int MF = RPW / 16;         // m fragments per wave
    constexpr int BN = 64 * WN;
    constexpr int CA = (BM / 16) / NW;   // A 16-row chunks per wave
    static_assert(BN / 16 <= NW, "B staging needs BN/16 <= NW");
    __shared__ unsigned short As[2][BM * 32];
    __shared__ unsigned short Bs[2][BN * 32];
    const int lane = threadIdx.x & 63;
    const int w = threadIdx.x >> 6;
    const int wr = w / WN, wc = w % WN;
    const int tm = blockIdx.y * BM;
    const int tn = blockIdx.x * BN;

    f32x4 acc[MF][4];
#pragma unroll
    for (int m = 0; m < MF; m++)
#pragma unroll
        for (int n = 0; n < 4; n++) acc[m][n] = (f32x4){0.f, 0.f, 0.f, 0.f};

    const int sRow = lane >> 2;
    const int sCol = (lane & 3) * 8;
    const int fragA = (wr * RPW + (lane & 15)) * 32 + (lane >> 4) * 8;
    const int fragB = (wc * 64 + (lane & 15)) * 32 + (lane >> 4) * 8;

    auto STAGE = [&](int k0, int buf) {
#pragma unroll
        for (int i = 0; i < CA; i++) {
            int chunk = w * CA + i;
            int r = chunk * 16 + sRow;
            gload_lds16(A + (size_t)(tm + r) * K + k0 + sCol, (void*)(As[buf] + chunk * 512));
        }
        if (w < BN / 16) {
            int r = w * 16 + sRow;
            gload_lds16(Bt + (size_t)(tn + r) * K + k0 + sCol, (void*)(Bs[buf] + w * 512));
        }
    };

    STAGE(0, 0);
    __syncthreads();
    int cur = 0;
    for (int k0 = 0; k0 < K; k0 += 32) {
        if (k0 + 32 < K) STAGE(k0 + 32, cur ^ 1);
        bf16x8 af[MF], bg[4];
#pragma unroll
        for (int m = 0; m < MF; m++) af[m] = *(const bf16x8*)(As[cur] + fragA + m * 16 * 32);
#pragma unroll
        for (int n = 0; n < 4; n++) bg[n] = *(const bf16x8*)(Bs[cur] + fragB + n * 16 * 32);
#pragma unroll
        for (int m = 0; m < MF; m++)
#pragma unroll
            for (int n = 0; n < 4; n++)
                acc[m][n] = __builtin_amdgcn_mfma_f32_16x16x32_bf16(af[m], bg[n], acc[m][n], 0, 0, 0);
        __syncthreads();
        cur ^= 1;
    }

#pragma unroll
    for (int m = 0; m < MF; m++) {
        int row = tm + wr * RPW + m * 16 + (lane >> 4) * 4;
#pragma unroll
        for (int n = 0; n < 4; n++) {
            int col = tn + wc * 64 + n * 16 + (lane & 15);
            if (EPI == 0) {
                int which = col >> 10;
                int hh = (col >> 6) & 15;
                int d = col & 63;
                int b0 = row >> 11;
                int nn = row & 2047;             // nn % 4 == 0
                size_t bh = (size_t)(b0 * 16 + hh);
                if (which == 2) {
                    int i6 = nn & 63;
                    int pc = (nn & ~63) + ((i6 >> 2) & 3) * 16 + ((i6 >> 4) & 3) * 4;
                    ushort4 st;
                    st.x = f2b(acc[m][n][0]);
                    st.y = f2b(acc[m][n][1]);
                    st.z = f2b(acc[m][n][2]);
                    st.w = f2b(acc[m][n][3]);
                    *(ushort4*)(outV + bh * 131072 + (size_t)d * 2048 + pc) = st;
                } else if (which == 0) {
                    size_t off = (bh * 2048 + nn) * 64 + d;
#pragma unroll
                    for (int r = 0; r < 4; r++)
                        outQ[off + (size_t)r * 64] = f2b(acc[m][n][r] * 0.125f);
                } else {
                    size_t off = (bh * 2048 + nn) * 64 + d;
#pragma unroll
                    for (int r = 0; r < 4; r++)
                        outK[off + (size_t)r * 64] = f2b(acc[m][n][r]);
                }
            } else {
#pragma unroll
                for (int r = 0; r < 4; r++)
                    outF[(size_t)(row + r) * N + col] = acc[m][n][r];
            }
        }
    }
}

// ---------------- flash attention (R23: Latin-square 1024 blocks) ----------------

__global__ __launch_bounds__(256)
void attn_kernel(const unsigned short* __restrict__ Q,
                 const unsigned short* __restrict__ Kg,
                 const unsigned short* __restrict__ Vp,
                 const float* __restrict__ Gates,
                 unsigned short* __restrict__ Out) {
    __shared__ unsigned short lds[2][2][64][64];   // [dbuf][K|V][row][col] = 32KB

    const int lane = threadIdx.x & 63;
    const int w = threadIdx.x >> 6;
    const int g = lane >> 4;
    const int ql = lane & 15;
    const int sw = ql & 7;
    const int srow = lane >> 3;
    const int sch = lane & 7;

    const int x = blockIdx.x & 7;            // XCD
    const int c = (blockIdx.x >> 3) & 31;    // CU within XCD
    const int j = blockIdx.x >> 8;           // co-residency round 0..3
    const int bh = x * 4 + (c & 3);
    const int s = c >> 2;                    // 0..7
    const int qt = (j == 0) ? (31 - s) : (j == 1) ? s : (j == 2) ? (23 - s) : (8 + s);
    const int b = bh >> 4;
    const int h = bh & 15;

    const size_t headBase = (size_t)bh * 2048 * 64;
    const size_t vBase = (size_t)bh * 131072;

    const int koff0 = ((g) ^ sw) * 8;
    const int koff1 = ((g + 4) ^ sw) * 8;
    const int voff0 = ((2 * g) ^ sw) * 8;
    const int voff1 = ((2 * g + 1) ^ sw) * 8;

    const int ch = sch ^ srow;
    const unsigned short* kSt0 = Kg + headBase + (size_t)(w * 16 + srow) * 64 + ch * 8;
    const unsigned short* kSt1 = kSt0 + 8 * 64;
    const unsigned short* vSt0 = Vp + vBase + (size_t)(w * 16 + srow) * 2048 + ch * 8;
    const unsigned short* vSt1 = vSt0 + 8 * 2048;

    auto STAGE = [&](int jn, int buf) {
        gload_lds16(kSt0 + (size_t)jn * 4096, (void*)&lds[buf][0][w * 16][0]);
        gload_lds16(kSt1 + (size_t)jn * 4096, (void*)&lds[buf][0][w * 16 + 8][0]);
        gload_lds16(vSt0 + jn * 64, (void*)&lds[buf][1][w * 16][0]);
        gload_lds16(vSt1 + jn * 64, (void*)&lds[buf][1][w * 16 + 8][0]);
    };

    const float LOG2E = 1.4426950408889634f;
    const float LC1 = -1.9235933878519511e-4f;   // LOG2E * -(1/3)/2500
    const float LC2 = 3.0777494205631219e-8f;    // LOG2E * (2/15)/2500^2

    const int qglob = qt * 64 + w * 16 + ql;
    const unsigned short* qp = Q + headBase + (size_t)qglob * 64 + g * 8;
    bf16x8 qa0 = *(const bf16x8*)qp;
    bf16x8 qa1 = *(const bf16x8*)(qp + 32);

    float lsum = 0.f;
    f32x4 o[4];
#pragma unroll
    for (int n = 0; n < 4; n++) o[n] = (f32x4){0.f, 0.f, 0.f, 0.f};

    auto COMPUTE = [&](int jt, int bb, bool diag) {
        const unsigned short* KL = &lds[bb][0][0][0];
        const unsigned short* VL = &lds[bb][1][0][0];

        f32x4 s4[4];
        __builtin_amdgcn_s_setprio(1);
#pragma unroll
        for (int n = 0; n < 4; n++) {
            const unsigned short* kr = KL + (16 * n + ql) * 64;
            bf16x8 k0 = *(const bf16x8*)(kr + koff0);
            bf16x8 k1 = *(const bf16x8*)(kr + koff1);
            f32x4 sv = (f32x4){0.f, 0.f, 0.f, 0.f};
            sv = __builtin_amdgcn_mfma_f32_16x16x32_bf16(k0, qa0, sv, 0, 0, 0);
            sv = __builtin_amdgcn_mfma_f32_16x16x32_bf16(k1, qa1, sv, 0, 0, 0);
            s4[n] = sv;
        }
        __builtin_amdgcn_s_setprio(0);

        float rs = 0.f;
#pragma unroll
        for (int n = 0; n < 4; n++) {
            int k0c = jt * 64 + n * 16 + 4 * g;
#pragma unroll
            for (int r = 0; r < 4; r++) {
                float xx = s4[n][r];
                float x2 = xx * xx;
                float e2 = xx * __builtin_fmaf(x2, __builtin_fmaf(x2, LC2, LC1), LOG2E);
                if (diag && (k0c + r > qglob)) e2 = -1e30f;
                float p = __builtin_amdgcn_exp2f(e2);
                s4[n][r] = p;
                rs += p;
            }
        }
        lsum += rs;

        union PU { unsigned int u[4]; bf16x8 v; };
        PU p0, p1;
        p0.u[0] = cvtpk(s4[0][0], s4[0][1]);
        p0.u[1] = cvtpk(s4[0][2], s4[0][3]);
        p0.u[2] = cvtpk(s4[1][0], s4[1][1]);
        p0.u[3] = cvtpk(s4[1][2], s4[1][3]);
        p1.u[0] = cvtpk(s4[2][0], s4[2][1]);
        p1.u[1] = cvtpk(s4[2][2], s4[2][3]);
        p1.u[2] = cvtpk(s4[3][0], s4[3][1]);
        p1.u[3] = cvtpk(s4[3][2], s4[3][3]);

        __builtin_amdgcn_s_setprio(1);
#pragma unroll
        for (int n = 0; n < 4; n++) {
            const unsigned short* vr = VL + (16 * n + ql) * 64;
            bf16x8 vA = *(const bf16x8*)(vr + voff0);
            bf16x8 vB = *(const bf16x8*)(vr + voff1);
            o[n] = __builtin_amdgcn_mfma_f32_16x16x32_bf16(vA, p0.v, o[n], 0, 0, 0);
            o[n] = __builtin_amdgcn_mfma_f32_16x16x32_bf16(vB, p1.v, o[n], 0, 0, 0);
        }
        __builtin_amdgcn_s_setprio(0);
    };

    STAGE(0, 0);
    __syncthreads();

    for (int jt = 0; jt < qt; ++jt) {
        const int bb = jt & 1;
        STAGE(jt + 1, bb ^ 1);
        COMPUTE(jt, bb, false);
        __syncthreads();
    }
    COMPUTE(qt, qt & 1, true);

    float l = lsum;
    l += __shfl_xor(l, 16);
    l += __shfl_xor(l, 32);
    float gate = Gates[(size_t)bh * 2048 + qglob];
    float inv = gate / l;
    unsigned short* orow = Out + ((size_t)(b * 2048) + qglob) * 1024 + h * 64;
#pragma unroll
    for (int n = 0; n < 4; n++) {
        ushort4 st;
        st.x = f2b(o[n][0] * inv);
        st.y = f2b(o[n][1] * inv);
        st.z = f2b(o[n][2] * inv);
        st.w = f2b(o[n][3] * inv);
        *(ushort4*)(orow + n * 16 + 4 * g) = st;
    }
}

// ---------------- launch ----------------

extern "C" void kernel_launch(void* const* d_in, const int* in_sizes, int n_in,
                              void* d_out, int out_size, void* d_ws, size_t ws_size,
                              hipStream_t stream) {
    const float* x       = (const float*)d_in[0];   // [2][2048][1024]
    const float* w_qkv   = (const float*)d_in[1];   // [1024][3072]
    const float* w_gates = (const float*)d_in[2];   // [1024][16]
    const float* w_out   = (const float*)d_in[3];   // [1024][1024]
    float* out = (float*)d_out;                     // [2][2048][1024]

    char* ws = (char*)d_ws;
    unsigned short* x_bf  = (unsigned short*)(ws);                      // 8 MB
    unsigned short* wqkvT = (unsigned short*)(ws + ((size_t)8  << 20)); // 6 MB
    unsigned short* woutT = (unsigned short*)(ws + ((size_t)14 << 20)); // 2 MB
    unsigned short* qB    = (unsigned short*)(ws + ((size_t)16 << 20)); // 8 MB
    unsigned short* kB    = (unsigned short*)(ws + ((size_t)24 << 20)); // 8 MB
    unsigned short* vP    = (unsigned short*)(ws + ((size_t)32 << 20)); // 8 MB (permuted V)
    float*          gates = (float*)(ws + ((size_t)40 << 20));          // 256 KB
    unsigned short* wgT   = (unsigned short*)(ws + ((size_t)40 << 20) + (512 << 10)); // 32 KB
    unsigned short* attnO = (unsigned short*)(ws + ((size_t)41 << 20)); // 8 MB

    prepass_kernel<<<dim3(6148), dim3(256), 0, stream>>>(
        x, w_gates, w_qkv, w_out, x_bf, wqkvT, woutT, wgT);

    gates_mfma_kernel<<<dim3(256), dim3(256), 0, stream>>>(x_bf, wgT, gates);

    gemm_bt_kernel<0, 128, 2, 8><<<dim3(3072 / 128, 4096 / 128), dim3(512), 0, stream>>>(
        x_bf, wqkvT, 4096, 3072, 1024, qB, kB, vP, (float*)nullptr);

    attn_kernel<<<dim3(1024), dim3(256), 0, stream>>>(qB, kB, vP, gates, attnO);

    gemm_bt_kernel<1, 128, 1, 4><<<dim3(1024 / 64, 4096 / 128), dim3(256), 0, stream>>>(
        attnO, woutT, 4096, 1024, 1024, nullptr, nullptr, nullptr, out);
}